// Round 14
// baseline (176.845 us; speedup 1.0000x reference)
//
#include <hip/hip_runtime.h>
#include <hip/hip_bf16.h>
#include <math.h>

#define L_TAU_C 0.8f

typedef _Float16 f16x8 __attribute__((ext_vector_type(8)));
typedef float f32x4 __attribute__((ext_vector_type(4)));
typedef unsigned int uint2a4 __attribute__((ext_vector_type(2), aligned(4)));
typedef unsigned int uint4e __attribute__((ext_vector_type(4)));

union U4H8 { uint4e u; f16x8 h; };
typedef _Float16 half2_t __attribute__((ext_vector_type(2)));
union U32H2 { unsigned int u; half2_t h; };

__device__ __forceinline__ float sigmoidf_(float x) {
    return 1.0f / (1.0f + __expf(-x));
}

// ---------------------------------------------------------------------------
// Kernel 1: transpose x [128][4096][20] f32 -> xT [128][20][4096] f16.
// ---------------------------------------------------------------------------
__global__ __launch_bounds__(256) void k_transpose16(const float* __restrict__ x,
                                                     _Float16* __restrict__ xT) {
    int gp = blockIdx.x * 256 + threadIdx.x;      // 0..524287
    int b = gp >> 12, p = gp & 4095;
    const float4* src = reinterpret_cast<const float4*>(x + (size_t)gp * 20);
    float v[20];
#pragma unroll
    for (int k = 0; k < 5; ++k) {
        float4 q = src[k];
        v[4 * k + 0] = q.x; v[4 * k + 1] = q.y; v[4 * k + 2] = q.z; v[4 * k + 3] = q.w;
    }
    _Float16* dst = xT + (size_t)b * 20 * 4096 + p;
#pragma unroll
    for (int t = 0; t < 20; ++t) dst[(size_t)t * 4096] = (_Float16)v[t];
}

// ---------------------------------------------------------------------------
// A-fragment loaders (R13-proven layout, absmax 0).
// lane l, slice q: elems 0-3 = x[ar+2q][acol+j], elems 4-7 = row +1.
// ---------------------------------------------------------------------------
__device__ __forceinline__ void loadA16(const _Float16* tb, int ar, f16x8* A) {
#pragma unroll
    for (int q = 0; q < 5; ++q) {
        int r0 = ar + 2 * q;     if (r0 > 63) r0 = 63;
        int r1 = ar + 2 * q + 1; if (r1 > 63) r1 = 63;
        uint2a4 lo = *reinterpret_cast<const uint2a4*>(tb + r0 * 64);
        uint2a4 hi = *reinterpret_cast<const uint2a4*>(tb + r1 * 64);
        U4H8 u; u.u = (uint4e){lo[0], lo[1], hi[0], hi[1]};
        A[q] = u.h;
    }
}

__device__ __forceinline__ void loadA32(const float* tb, int ar, int acol,
                                        f16x8* A) {
#pragma unroll
    for (int q = 0; q < 5; ++q) {
        f16x8 av;
#pragma unroll
        for (int j = 0; j < 8; ++j) {
            int r = ar + 2 * q + (j >> 2); if (r > 63) r = 63;
            av[j] = (_Float16)tb[(size_t)(r * 64 + acol + (j & 3)) * 20];
        }
        A[q] = av;
    }
}

// ---------------------------------------------------------------------------
// Kernel 2: MFMA implicit-GEMM conv + SNU + maxpool + partial FC dot,
// SOFTWARE-PIPELINED over t (R13 post-mortem: no pipe saturated -- the wall
// was per-t load latency with ~2 waves/SIMD; A addresses depend only on t,
// so prefetch t+1's A (named double buffer A0/A1, pair-stepped loop, all
// compile-time indices) while t computes. Compiler emits vmcnt(10) waits
// leaving the next 10 loads in flight under MFMA+SNU+reduce.)
// Implicit GEMM layout and everything else = R13 (passed, absmax 0).
// ---------------------------------------------------------------------------
template<int XMODE>   // 1 = f16 transposed input, 0 = strided f32 fallback
__global__ __launch_bounds__(256) void k_conv_snu(
    const float* __restrict__ x,      // [128][4096][20]
    const _Float16* __restrict__ xT,  // [128][20][4096]
    const float* __restrict__ Wc,     // [6][1][10][10]
    const float* __restrict__ bc,     // [6]
    const float* __restrict__ W2,     // [4374][2]
    float* __restrict__ partw)        // [20][128][9][4][2]
{
    const int tid = threadIdx.x;
    const int bi = blockIdx.x;                 // 0..1151
    const int xcd = bi & 7, slot = bi >> 3;    // slot 0..143
    const int b = (slot / 9) * 8 + xcd;        // all 9 jg of b on same XCD
    const int jg = slot % 9;                   // conv cols 6jg..6jg+5
    const int w = tid >> 6;                    // wave = row strip 0..3
    const int l = tid & 63;
    const int RS = 16 * w;
    const int C0 = 6 * jg;
    const int n = l & 15, lh = l >> 4;
    const int ch = n >> 1, e = n & 1;

    // ---- B fragments: built once, constant over t ----
    f16x8 Bf[3][5];
#pragma unroll
    for (int s = 0; s < 3; ++s) {
#pragma unroll
        for (int q = 0; q < 5; ++q) {
            f16x8 bv;
#pragma unroll
            for (int j = 0; j < 8; ++j) {
                int wr = 2 * q + (j >> 2);
                int wc = 4 * lh + (j & 3);
                int wcd = wc - (2 * s + e);
                float wv = 0.f;
                if (ch < 6 && wcd >= 0 && wcd < 10)
                    wv = Wc[ch * 100 + wr * 10 + wcd];
                bv[j] = (_Float16)wv;
            }
            Bf[s][q] = bv;
        }
    }

    // ---- SNU state (3 sets x 4 rows per lane) ----
    float sA[3][4], yA[3][4];
#pragma unroll
    for (int s = 0; s < 3; ++s)
#pragma unroll
        for (int g = 0; g < 4; ++g) { sA[s][g] = 0.f; yA[s][g] = 0.f; }

    const float bch = (ch < 6) ? bc[ch] : 0.f;

    // ---- FC weights, fully masked ----
    float w2v[3][2][2];
#pragma unroll
    for (int s = 0; s < 3; ++s)
#pragma unroll
        for (int m = 0; m < 2; ++m) {
            int prow = 8 * w + 2 * lh + m;
            int pcol = 3 * jg + s;
            float a0 = 0.f, a1 = 0.f;
            if (e == 0 && ch < 6 && prow < 27) {
                int f = ch * 729 + prow * 27 + pcol;
                a0 = W2[(size_t)f * 2 + 0];
                a1 = W2[(size_t)f * 2 + 1];
            }
            w2v[s][m][0] = a0; w2v[s][m][1] = a1;
        }

    const _Float16* xb16 = xT + (size_t)b * 20 * 4096;
    const float* xb32 = x + (size_t)b * 4096 * 20;
    const int ar = RS + (l & 15);
    const int acol = C0 + 4 * lh;

    // per-t compute, consumes one A buffer
    auto step_t = [&](const f16x8* Af, int t) {
        f32x4 acc[3];
#pragma unroll
        for (int s = 0; s < 3; ++s) acc[s] = (f32x4){0.f, 0.f, 0.f, 0.f};
#pragma unroll
        for (int q = 0; q < 5; ++q) {
#pragma unroll
            for (int s = 0; s < 3; ++s)
                acc[s] = __builtin_amdgcn_mfma_f32_16x16x32_f16(
                    Af[q], Bf[s][q], acc[s], 0, 0, 0);
        }
        float p0 = 0.f, p1 = 0.f;
#pragma unroll
        for (int s = 0; s < 3; ++s) {
#pragma unroll
            for (int g = 0; g < 4; ++g) {
                float sa = fmaxf(acc[s][g] + L_TAU_C * sA[s][g] * (1.f - yA[s][g]), 0.f);
                sA[s][g] = sa;
                yA[s][g] = sigmoidf_(sa + bch);
            }
            float m0 = fmaxf(yA[s][0], yA[s][1]);
            float m1 = fmaxf(yA[s][2], yA[s][3]);
            float h0 = fmaxf(m0, __shfl_xor(m0, 1));
            float h1 = fmaxf(m1, __shfl_xor(m1, 1));
            p0 += h0 * w2v[s][0][0] + h1 * w2v[s][1][0];
            p1 += h0 * w2v[s][0][1] + h1 * w2v[s][1][1];
        }
#pragma unroll
        for (int off = 32; off >= 1; off >>= 1) {
            p0 += __shfl_down(p0, off);
            p1 += __shfl_down(p1, off);
        }
        if (l == 0) {
            float2 val; val.x = p0; val.y = p1;
            *reinterpret_cast<float2*>(
                &partw[((((size_t)t * 128 + b) * 9 + jg) * 4 + w) * 2]) = val;
        }
    };

    // ---- pair-stepped pipelined t loop: named double buffers A0/A1 ----
    f16x8 A0[5], A1[5];
    if (XMODE == 1) loadA16(xb16 + acol, ar, A0);
    else            loadA32(xb32, ar, acol, A0);

    for (int tp = 0; tp < 10; ++tp) {
        const int t0 = 2 * tp, t1 = 2 * tp + 1;
        // prefetch t1 while t0 computes
        if (XMODE == 1) loadA16(xb16 + (size_t)t1 * 4096 + acol, ar, A1);
        else            loadA32(xb32 + t1, ar, acol, A1);
        step_t(A0, t0);
        // prefetch t1+1 while t1 computes
        if (t1 < 19) {
            if (XMODE == 1) loadA16(xb16 + (size_t)(t1 + 1) * 4096 + acol, ar, A0);
            else            loadA32(xb32 + t1 + 1, ar, acol, A0);
        }
        step_t(A1, t1);
    }
}

// ---------------------------------------------------------------------------
// Kernel 3: s2/y2 recurrence, out_rec, m, loss, acc. One block, 128 threads.
// ---------------------------------------------------------------------------
__global__ __launch_bounds__(128) void k_final(const float* __restrict__ partw,
                                               const void* __restrict__ yraw,
                                               const float* __restrict__ b2,
                                               float* __restrict__ out) {
    __shared__ float red[4];
    const int b = threadIdx.x;  // 0..127

    const int* yi = (const int*)yraw;
    bool i64 = true;
    for (int k = 0; k < 64; ++k) {
        if (yi[2 * k + 1] != 0) { i64 = false; break; }
    }
    int lbl = i64 ? (int)((const long long*)yraw)[b] : yi[b];

    float b20 = b2[0], b21 = b2[1];
    float s20 = 0.f, s21 = 0.f, y20 = 0.f, y21 = 0.f, m0 = 0.f, m1 = 0.f;
    float* orec = out + 257 + b * 42;
    orec[0] = 0.f; orec[1] = 0.f;
    for (int t = 0; t < 20; ++t) {
        const float4* pp = reinterpret_cast<const float4*>(
            partw + ((size_t)t * 128 + b) * 72);
        float sum0 = 0.f, sum1 = 0.f;
#pragma unroll
        for (int i = 0; i < 18; ++i) {
            float4 a = pp[i];
            sum0 += a.x + a.z;
            sum1 += a.y + a.w;
        }
        s20 = fmaxf(sum0 + L_TAU_C * s20 * (1.f - y20), 0.f);
        s21 = fmaxf(sum1 + L_TAU_C * s21 * (1.f - y21), 0.f);
        y20 = sigmoidf_(s20 + b20);
        y21 = sigmoidf_(s21 + b21);
        orec[(t + 1) * 2 + 0] = y20;
        orec[(t + 1) * 2 + 1] = y21;
        m0 += y20; m1 += y21;
    }
    m0 *= 0.05f; m1 *= 0.05f;
    out[1 + b * 2 + 0] = m0;
    out[1 + b * 2 + 1] = m1;

    float mx = fmaxf(m0, m1);
    float lse = mx + logf(expf(m0 - mx) + expf(m1 - mx));
    float lossc = -(((lbl != 0) ? m1 : m0) - lse);
    int pred = (m1 > m0) ? 1 : 0;
    float accc = (pred == lbl) ? 1.f : 0.f;
#pragma unroll
    for (int off = 32; off >= 1; off >>= 1) {
        lossc += __shfl_down(lossc, off);
        accc += __shfl_down(accc, off);
    }
    if ((b & 63) == 0) { red[(b >> 6) * 2] = lossc; red[(b >> 6) * 2 + 1] = accc; }
    __syncthreads();
    if (b == 0) {
        out[0] = (red[0] + red[2]) * (1.f / 128.f);
        out[5633] = (red[1] + red[3]) * (1.f / 128.f);
    }
}

extern "C" void kernel_launch(void* const* d_in, const int* in_sizes, int n_in,
                              void* d_out, int out_size, void* d_ws, size_t ws_size,
                              hipStream_t stream) {
    const float* x  = (const float*)d_in[0];
    const void*  y  = d_in[1];
    const float* Wc = (const float*)d_in[2];
    const float* bc = (const float*)d_in[3];
    const float* W2 = (const float*)d_in[4];
    const float* b2 = (const float*)d_in[5];
    float* out = (float*)d_out;

    const size_t xt_bytes = (size_t)128 * 20 * 4096 * 2;         // 20,971,520
    const size_t partw_bytes = (size_t)20 * 128 * 9 * 4 * 2 * 4; // 737,280
    const int use16 = (ws_size >= xt_bytes + partw_bytes) ? 1 : 0;

    _Float16* xT = (_Float16*)d_ws;
    float* partw = use16 ? (float*)((char*)d_ws + xt_bytes) : (float*)d_ws;

    if (use16) {
        k_transpose16<<<2048, 256, 0, stream>>>(x, xT);
        k_conv_snu<1><<<1152, 256, 0, stream>>>(x, xT, Wc, bc, W2, partw);
    } else {
        k_conv_snu<0><<<1152, 256, 0, stream>>>(x, (const _Float16*)d_ws, Wc, bc, W2, partw);
    }
    k_final<<<1, 128, 0, stream>>>(partw, y, b2, out);
}